// Round 5
// baseline (332.309 us; speedup 1.0000x reference)
//
#include <hip/hip_runtime.h>
#include <hip/hip_bf16.h>

#define N_NODES 100000
#define DIM 64
#define SCAN_B 256

#define RANGE_NODES 50000   // node-range per histogram block (50KB LDS bytes)
#define HWORDS 12500        // RANGE_NODES/4 packed-byte words
#define HCHUNKS 64          // edge chunks per (array,range)
#define SCHUNKS 128         // edge chunks for bin scatter
#define BINSZ 512           // dst nodes per bin
#define NBINS 196           // ceil(N_NODES/BINSZ)

#define NBATCH 6250         // 100000 / 16 node-batches (exact)

typedef __attribute__((ext_vector_type(8))) short short8v;
typedef __attribute__((ext_vector_type(4))) float float4v;

// ---------------------------------------------------------------------------
// Packed-byte histogram, one launch: blocks [0,128) = src, [128,256) = dst.
// ---------------------------------------------------------------------------
__global__ __launch_bounds__(256) void hist_kernel(
    const int* __restrict__ src, const int* __restrict__ dst, int nkeys,
    unsigned int* __restrict__ partials) {
  __shared__ unsigned int h[HWORDS];
  int which = blockIdx.x >> 7;             // 0 = src, 1 = dst
  int local = blockIdx.x & 127;
  int range = local >> 6;
  int chunk = local & 63;
  const int* keys = which ? dst : src;
  int lo = range * RANGE_NODES;
  for (int i = threadIdx.x; i < HWORDS; i += 256) h[i] = 0;
  __syncthreads();
  int per = (nkeys + HCHUNKS - 1) / HCHUNKS;
  int beg = chunk * per;
  int end = min(beg + per, nkeys);
  for (int i = beg + threadIdx.x; i < end; i += 256) {
    int k = keys[i] - lo;
    if ((unsigned)k < (unsigned)RANGE_NODES)
      atomicAdd(&h[k >> 2], 1u << ((k & 3) * 8));
  }
  __syncthreads();
  unsigned int* outp = partials + (size_t)blockIdx.x * HWORDS;
  for (int i = threadIdx.x; i < HWORDS; i += 256) outp[i] = h[i];
}

// ---------------------------------------------------------------------------
// Sum 64 chunk-partials per word, unpack bytes -> sn / dn / ideg.
// ---------------------------------------------------------------------------
__global__ __launch_bounds__(256) void reduce_norm_kernel(
    const unsigned int* __restrict__ ps, const unsigned int* __restrict__ pd,
    float* __restrict__ sn, float* __restrict__ dn, int* __restrict__ ideg) {
  int w = blockIdx.x * 256 + threadIdx.x;
  if (w >= 2 * (N_NODES / 4)) return;
  int is_dst = (w >= N_NODES / 4);
  int lw = is_dst ? w - N_NODES / 4 : w;
  const unsigned int* p = is_dst ? pd : ps;
  int r = lw / HWORDS, wr = lw % HWORDS;
  const unsigned int* base = p + (size_t)(r * HCHUNKS) * HWORDS + wr;
  unsigned int s0 = 0, s1 = 0, s2 = 0, s3 = 0;
  for (int c = 0; c < HCHUNKS; ++c) {
    unsigned int v = base[(size_t)c * HWORDS];
    s0 += v & 255u; s1 += (v >> 8) & 255u; s2 += (v >> 16) & 255u; s3 += v >> 24;
  }
  unsigned int d[4] = {s0, s1, s2, s3};
  int n0 = r * RANGE_NODES + wr * 4;
#pragma unroll
  for (int j = 0; j < 4; ++j) {
    int n = n0 + j;
    float f = (d[j] > 0) ? rsqrtf((float)d[j]) : 0.0f;
    if (is_dst) { dn[n] = f; ideg[n] = (int)d[j]; }
    else        { sn[n] = f; }
  }
}

// ---------------------------------------------------------------------------
// xb[n][k] = bf16( x[n][k] * sn[n] )  — prescaled bf16 gather operand.
// ---------------------------------------------------------------------------
__global__ __launch_bounds__(256) void convert_prescale_kernel(
    const float* __restrict__ x, const float* __restrict__ sn,
    unsigned int* __restrict__ xb2, int nquads) {
  int i = blockIdx.x * 256 + threadIdx.x;
  if (i >= nquads) return;
  float s = sn[i >> 4];                       // node = (i*4)/64
  float4 v = ((const float4*)x)[i];
  __hip_bfloat162 a = __float22bfloat162_rn(make_float2(v.x * s, v.y * s));
  __hip_bfloat162 b = __float22bfloat162_rn(make_float2(v.z * s, v.w * s));
  unsigned int wa, wb;
  __builtin_memcpy(&wa, &a, 4);
  __builtin_memcpy(&wb, &b, 4);
  ((uint2*)xb2)[i] = make_uint2(wa, wb);
}

// ---------------------------------------------------------------------------
// Exclusive scan, 3-kernel classic (n = 100000, nb = 391).
// ---------------------------------------------------------------------------
__global__ __launch_bounds__(SCAN_B) void scan_block_kernel(
    const int* __restrict__ in, int* __restrict__ out,
    int* __restrict__ bsum, int n) {
  __shared__ int s[SCAN_B];
  int t = threadIdx.x;
  int i = blockIdx.x * SCAN_B + t;
  int v = (i < n) ? in[i] : 0;
  s[t] = v;
  __syncthreads();
  for (int off = 1; off < SCAN_B; off <<= 1) {
    int add = (t >= off) ? s[t - off] : 0;
    __syncthreads();
    s[t] += add;
    __syncthreads();
  }
  if (i < n) out[i] = s[t] - v;
  if (t == SCAN_B - 1) bsum[blockIdx.x] = s[t];
}

__global__ __launch_bounds__(512) void scan_top_kernel(
    int* __restrict__ bsum, int nb) {
  __shared__ int s[512];
  int t = threadIdx.x;
  int v = (t < nb) ? bsum[t] : 0;
  s[t] = v;
  __syncthreads();
  for (int off = 1; off < 512; off <<= 1) {
    int add = (t >= off) ? s[t - off] : 0;
    __syncthreads();
    s[t] += add;
    __syncthreads();
  }
  if (t < nb) bsum[t] = s[t] - v;
}

__global__ __launch_bounds__(256) void scan_add_kernel(
    int* __restrict__ out, const int* __restrict__ bsum, int n, int total) {
  int i = blockIdx.x * blockDim.x + threadIdx.x;
  if (i < n) out[i] += bsum[i / SCAN_B];
  if (i == 0) out[n] = total;
}

// ---------------------------------------------------------------------------
// Partition edges into NBINS dst-bins.
// ---------------------------------------------------------------------------
__global__ __launch_bounds__(256) void bin_scatter_kernel(
    const int* __restrict__ src, const int* __restrict__ dst,
    const int* __restrict__ offsets, int* __restrict__ bin_cursor,
    int2* __restrict__ binned, int E) {
  __shared__ int cnt[NBINS];
  __shared__ int base[NBINS];
  int t = threadIdx.x;
  for (int i = t; i < NBINS; i += 256) cnt[i] = 0;
  __syncthreads();
  int per = (E + SCHUNKS - 1) / SCHUNKS;
  int beg = blockIdx.x * per;
  int end = min(beg + per, E);
  for (int i = beg + t; i < end; i += 256)
    atomicAdd(&cnt[dst[i] >> 9], 1);
  __syncthreads();
  for (int i = t; i < NBINS; i += 256) {
    base[i] = offsets[i << 9] + atomicAdd(&bin_cursor[i], cnt[i]);
    cnt[i] = 0;
  }
  __syncthreads();
  for (int i = beg + t; i < end; i += 256) {
    int s = src[i], d = dst[i];
    int b = d >> 9;
    int r = atomicAdd(&cnt[b], 1);
    binned[base[b] + r] = make_int2(s, d);
  }
}

// ---------------------------------------------------------------------------
// CSR fill, one block per bin.
// ---------------------------------------------------------------------------
__global__ __launch_bounds__(256) void fill_binned_kernel(
    const int2* __restrict__ binned, const int* __restrict__ offsets,
    int* __restrict__ csr_src) {
  __shared__ int cur[BINSZ];
  __shared__ int offs[BINSZ];
  int b = blockIdx.x;
  int t = threadIdx.x;
  int lo = b << 9;
  for (int i = t; i < BINSZ; i += 256) {
    cur[i] = 0;
    offs[i] = offsets[min(lo + i, N_NODES)];
  }
  __syncthreads();
  int w0 = offsets[lo];
  int w1 = offsets[min(lo + BINSZ, N_NODES)];
  for (int e = w0 + t; e < w1; e += 256) {
    int2 sd = binned[e];
    int r = atomicAdd(&cur[sd.y - lo], 1);
    csr_src[offs[sd.y - lo] + r] = sd.x;
  }
}

// ---------------------------------------------------------------------------
// Fused layer v6: wave per 16-node batch; MFMA projection; concurrency fixed.
//   v5 regression diagnosed: occupancy 38->23% (one batch/wave + LDS churn)
//   dropped miss-path BW 2.0->1.34 TB/s. Fixes:
//   - per-node tail = ONE float4 LDS write (f32, x dn); the f32->bf16 hi/lo
//     conversion moved to the projection phase (all 64 lanes parallel).
//   - grid = 1280 blocks (exactly 5 blocks/CU at 32KB LDS), grid-stride:
//     ~5 batches per block amortize W staging; 20 resident waves/CU.
//   Numerically proven parts kept verbatim: gather loop, W-staging layout,
//   MFMA call pattern (Ahi*Wh + Alo*Wh + Ahi*Wl), epilogue mapping.
// ---------------------------------------------------------------------------
__device__ __forceinline__ float bf_lo(unsigned int u) {
  unsigned int x = u << 16; float f; __builtin_memcpy(&f, &x, 4); return f;
}
__device__ __forceinline__ float bf_hi(unsigned int u) {
  unsigned int x = u & 0xffff0000u; float f; __builtin_memcpy(&f, &x, 4); return f;
}
__device__ __forceinline__ unsigned short bf16bits(float f) {
  __hip_bfloat16 h = __float2bfloat16(f);
  unsigned short u; __builtin_memcpy(&u, &h, 2); return u;
}

template <bool PRESCALE, typename OUT_T>
__device__ __forceinline__ void epilogue_nt(
    float4v acc, float bv, int nb16, int kq, int lane, float snb,
    OUT_T* __restrict__ out, int nt) {
  int col = nt * 16 + (lane & 15);
#pragma unroll
  for (int r = 0; r < 4; ++r) {
    int node = nb16 + kq * 4 + r;          // C/D row = (lane>>4)*4 + reg
    float o = fmaxf(acc[r] + bv, 0.0f);
    if (PRESCALE) {
      o = o * __shfl(snb, kq * 4 + r);
      out[(long)node * DIM + col] = (OUT_T)__float2bfloat16(o);
    } else {
      out[(long)node * DIM + col] = (OUT_T)o;
    }
  }
}

template <bool PRESCALE, typename OUT_T>
__global__ __launch_bounds__(256) void fused_layer_kernel(
    const __hip_bfloat16* __restrict__ xb, const int* __restrict__ csr_src,
    const int* __restrict__ offsets, const float* __restrict__ sn,
    const float* __restrict__ dn, const float* __restrict__ W,
    const float* __restrict__ bias, OUT_T* __restrict__ out, int N) {
  // W B-fragments: [hl][ntile][ktile][lane][8 bf16] = 16 KiB
  __shared__ __align__(16) short Wfrag[2][4][2][64][8];
  // Aggregated rows, f32, per wave-slot: [node 16][feat 64] = 4 KiB x 4
  __shared__ __align__(16) float Af32[4][16][64];

  int t = threadIdx.x;
  int lane = t & 63;
  int wslot = t >> 6;
  int g = lane >> 4;           // edge sub-slot 0..3  (also MFMA k-group)
  int q = lane & 15;           // feature quad: features 4q..4q+3

  // --- stage W as hi/lo bf16 B-fragments (once per block) ---
  for (int e = t; e < 1024; e += 256) {
    int lidx = e & 63;
    int f = e >> 6;                       // 0..15
    int ktv = f & 1, ntv = (f >> 1) & 3, hl = f >> 3;
#pragma unroll
    for (int j = 0; j < 8; ++j) {
      int k = ktv * 32 + (lidx >> 4) * 8 + j;   // consecutive-K lane layout
      int c = ntv * 16 + (lidx & 15);
      float w = W[k * DIM + c];
      unsigned short hb = bf16bits(w);
      if (hl == 0) {
        Wfrag[0][ntv][ktv][lidx][j] = (short)hb;
      } else {
        unsigned int hx = (unsigned int)hb << 16;
        float hf; __builtin_memcpy(&hf, &hx, 4);
        Wfrag[1][ntv][ktv][lidx][j] = (short)bf16bits(w - hf);
      }
    }
  }
  __syncthreads();

  float bias_nt[4];
#pragma unroll
  for (int nt = 0; nt < 4; ++nt) bias_nt[nt] = bias[nt * 16 + (lane & 15)];

  const uint2* __restrict__ xr = (const uint2*)xb;   // one row = 16 uint2
  char* abase = (char*)&Af32[wslot][0][0];           // 256 B per node row

  int nwaves = gridDim.x * 4;
  for (int nb = blockIdx.x * 4 + wslot; nb < NBATCH; nb += nwaves) {
    int nb16 = nb * 16;
    // batch-wide CSR offsets (lanes 0..16) + per-node norms via shfl
    int offv = offsets[nb16 + min(lane, 16)];
    float dnv = dn[nb16 + (lane & 15)];
    float snb = PRESCALE ? sn[nb16 + (lane & 15)] : 0.0f;

    // ---- gather 16 nodes (proven structure, unchanged) ----
    for (int ni = 0; ni < 16; ++ni) {
      int beg = __shfl(offv, ni);
      int end = __shfl(offv, ni + 1);
      float a0 = 0.f, a1 = 0.f, a2 = 0.f, a3 = 0.f;
      for (int base = beg; base < end; base += 16) {
        int j0 = base + g;
        int jm = end - 1;
        bool p0 = j0 < end, p1 = j0 + 4 < end, p2 = j0 + 8 < end,
             p3 = j0 + 12 < end;
        int s0 = csr_src[min(j0, jm)];
        int s1 = csr_src[min(j0 + 4, jm)];
        int s2 = csr_src[min(j0 + 8, jm)];
        int s3 = csr_src[min(j0 + 12, jm)];
        uint2 v0 = make_uint2(0u, 0u), v1 = v0, v2 = v0, v3 = v0;
        if (p0) v0 = xr[(size_t)s0 * 16 + q];
        if (p1) v1 = xr[(size_t)s1 * 16 + q];
        if (p2) v2 = xr[(size_t)s2 * 16 + q];
        if (p3) v3 = xr[(size_t)s3 * 16 + q];
        a0 += bf_lo(v0.x); a1 += bf_hi(v0.x); a2 += bf_lo(v0.y); a3 += bf_hi(v0.y);
        a0 += bf_lo(v1.x); a1 += bf_hi(v1.x); a2 += bf_lo(v1.y); a3 += bf_hi(v1.y);
        a0 += bf_lo(v2.x); a1 += bf_hi(v2.x); a2 += bf_lo(v2.y); a3 += bf_hi(v2.y);
        a0 += bf_lo(v3.x); a1 += bf_hi(v3.x); a2 += bf_lo(v3.y); a3 += bf_hi(v3.y);
      }
      a0 += __shfl_xor(a0, 16); a1 += __shfl_xor(a1, 16);
      a2 += __shfl_xor(a2, 16); a3 += __shfl_xor(a3, 16);
      a0 += __shfl_xor(a0, 32); a1 += __shfl_xor(a1, 32);
      a2 += __shfl_xor(a2, 32); a3 += __shfl_xor(a3, 32);

      float dnw = __shfl(dnv, ni);
      if (lane < 16) {
        // single f32x4 write; XOR swizzle in 32B units within the 256B row
        int woff = ni * 256 + ((q * 16) ^ ((ni & 7) << 5));
        *(float4*)(abase + woff) =
            make_float4(a0 * dnw, a1 * dnw, a2 * dnw, a3 * dnw);
      }
    }

    // ---- project: f32 rows -> hi/lo bf16 frags (parallel) -> 24 MFMA ----
    int r = lane & 15;
    float4v acc0 = {0.f, 0.f, 0.f, 0.f}, acc1 = acc0, acc2 = acc0, acc3 = acc0;
#pragma unroll
    for (int kt = 0; kt < 2; ++kt) {
      int f0b = kt * 128 + g * 32;               // byte offset of 8 feats
      int roff = r * 256 + (f0b ^ ((r & 7) << 5));
      float4 fa = *(float4*)(abase + roff);       // same-wave LDS, lgkm-ordered
      float4 fb = *(float4*)(abase + roff + 16);
      float fv[8] = {fa.x, fa.y, fa.z, fa.w, fb.x, fb.y, fb.z, fb.w};
      union { unsigned int w[4]; short8v v; } Uh, Ul;
#pragma unroll
      for (int p = 0; p < 4; ++p) {
        unsigned int u0, u1;
        __builtin_memcpy(&u0, &fv[2 * p], 4);
        __builtin_memcpy(&u1, &fv[2 * p + 1], 4);
        unsigned int h0 = u0 & 0xffff0000u, h1 = u1 & 0xffff0000u;
        Uh.w[p] = (h0 >> 16) | h1;                // packed hi (truncated)
        float hf0, hf1;
        __builtin_memcpy(&hf0, &h0, 4);
        __builtin_memcpy(&hf1, &h1, 4);
        __hip_bfloat162 lo2 = __float22bfloat162_rn(
            make_float2(fv[2 * p] - hf0, fv[2 * p + 1] - hf1));
        __builtin_memcpy(&Ul.w[p], &lo2, 4);      // packed lo (residual, RNE)
      }
      short8v ahi = Uh.v, alo = Ul.v;
#define PROJ_NT(NT, ACC)                                                      \
      {                                                                       \
        short8v bh = *(short8v*)&Wfrag[0][NT][kt][lane][0];                   \
        short8v bl = *(short8v*)&Wfrag[1][NT][kt][lane][0];                   \
        ACC = __builtin_amdgcn_mfma_f32_16x16x32_bf16(ahi, bh, ACC, 0, 0, 0); \
        ACC = __builtin_amdgcn_mfma_f32_16x16x32_bf16(alo, bh, ACC, 0, 0, 0); \
        ACC = __builtin_amdgcn_mfma_f32_16x16x32_bf16(ahi, bl, ACC, 0, 0, 0); \
      }
      PROJ_NT(0, acc0)
      PROJ_NT(1, acc1)
      PROJ_NT(2, acc2)
      PROJ_NT(3, acc3)
#undef PROJ_NT
    }

    float snbv = PRESCALE ? snb : 0.0f;
    epilogue_nt<PRESCALE, OUT_T>(acc0, bias_nt[0], nb16, g, lane, snbv, out, 0);
    epilogue_nt<PRESCALE, OUT_T>(acc1, bias_nt[1], nb16, g, lane, snbv, out, 1);
    epilogue_nt<PRESCALE, OUT_T>(acc2, bias_nt[2], nb16, g, lane, snbv, out, 2);
    epilogue_nt<PRESCALE, OUT_T>(acc3, bias_nt[3], nb16, g, lane, snbv, out, 3);
  }
}

extern "C" void kernel_launch(void* const* d_in, const int* in_sizes, int n_in,
                              void* d_out, int out_size, void* d_ws, size_t ws_size,
                              hipStream_t stream) {
  const float* x        = (const float*)d_in[0];
  const int*   edge_src = (const int*)d_in[1];
  const int*   edge_dst = (const int*)d_in[2];
  const float* W1       = (const float*)d_in[3];
  const float* b1       = (const float*)d_in[4];
  const float* W2       = (const float*)d_in[5];
  const float* b2       = (const float*)d_in[6];
  float* out = (float*)d_out;

  const int E = in_sizes[1];
  const int N = N_NODES;
  const int NB = (N + SCAN_B - 1) / SCAN_B;   // 391

  // Workspace (4B units), ~33.6 MB total. regionB time-shared:
  //   partials (hist..reduce) -> binned (bin_scatter..fill) -> h1b (layers)
  float* sn         = (float*)d_ws;                  // N
  float* dn         = sn + N;                        // N
  int*   ideg       = (int*)(dn + N);                // N
  int*   offsets    = ideg + N;                      // N+1
  int*   bsum       = offsets + (N + 1);             // 512
  int*   bin_cursor = bsum + 512;                    // 256
  int*   csr_src    = bin_cursor + 256;              // E
  unsigned int* xb_raw = (unsigned int*)(csr_src + E);       // N*DIM/2 (12.8MB)
  unsigned int* regionB = xb_raw + (size_t)N * DIM / 2;      // 12.8MB
  unsigned int* partials = regionB;                          // 256*HWORDS
  int2*  binned   = (int2*)regionB;                  // E int2
  __hip_bfloat16* xb  = (__hip_bfloat16*)xb_raw;
  __hip_bfloat16* h1b = (__hip_bfloat16*)regionB;

  hipMemsetAsync(bin_cursor, 0, 256 * sizeof(int), stream);

  // --- degrees + norms (no global atomics) ---
  hist_kernel<<<256, 256, 0, stream>>>(edge_src, edge_dst, E, partials);
  reduce_norm_kernel<<<(2 * (N / 4) + 255) / 256, 256, 0, stream>>>(
      partials, partials + (size_t)128 * HWORDS, sn, dn, ideg);

  // --- prescaled bf16 copy of x ---
  {
    int nquads = N * DIM / 4;
    convert_prescale_kernel<<<(nquads + 255) / 256, 256, 0, stream>>>(
        x, sn, xb_raw, nquads);
  }

  // --- offsets = exclusive scan of in-degree ---
  scan_block_kernel<<<NB, SCAN_B, 0, stream>>>(ideg, offsets, bsum, N);
  scan_top_kernel<<<1, 512, 0, stream>>>(bsum, NB);
  scan_add_kernel<<<(N + 255) / 256, 256, 0, stream>>>(offsets, bsum, N, E);

  // --- binned CSR build (overwrites partials region — dead after reduce) ---
  bin_scatter_kernel<<<SCHUNKS, 256, 0, stream>>>(edge_src, edge_dst, offsets,
                                                  bin_cursor, binned, E);
  fill_binned_kernel<<<NBINS, 256, 0, stream>>>(binned, offsets, csr_src);

  const int fb = 1280;   // 5 blocks/CU (32KB LDS limit), grid-stride batches

  // --- layer 1: xb -> h1b (bf16, prescaled by sn; overwrites binned) ---
  fused_layer_kernel<true, __hip_bfloat16><<<fb, 256, 0, stream>>>(
      xb, csr_src, offsets, sn, dn, W1, b1, h1b, N);

  // --- layer 2: h1b -> out (fp32) ---
  fused_layer_kernel<false, float><<<fb, 256, 0, stream>>>(
      h1b, csr_src, offsets, sn, dn, W2, b2, out, N);
}

// Round 6
// 314.755 us; speedup vs baseline: 1.0558x; 1.0558x over previous
//
#include <hip/hip_runtime.h>
#include <hip/hip_bf16.h>

#define N_NODES 100000
#define DIM 64
#define SCAN_B 256

#define RANGE_NODES 50000   // node-range per histogram block (50KB LDS bytes)
#define HWORDS 12500        // RANGE_NODES/4 packed-byte words
#define HCHUNKS 64          // edge chunks per (array,range)
#define SCHUNKS 128         // edge chunks for bin scatter
#define BINSZ 512           // dst nodes per bin
#define NBINS 196           // ceil(N_NODES/BINSZ)

#define NBATCH 6250         // 100000 / 16 node-batches (exact)

typedef __attribute__((ext_vector_type(8))) short short8v;
typedef __attribute__((ext_vector_type(4))) float float4v;

// ---------------------------------------------------------------------------
// Packed-byte histogram, one launch: blocks [0,128) = src, [128,256) = dst.
// ---------------------------------------------------------------------------
__global__ __launch_bounds__(256) void hist_kernel(
    const int* __restrict__ src, const int* __restrict__ dst, int nkeys,
    unsigned int* __restrict__ partials) {
  __shared__ unsigned int h[HWORDS];
  int which = blockIdx.x >> 7;             // 0 = src, 1 = dst
  int local = blockIdx.x & 127;
  int range = local >> 6;
  int chunk = local & 63;
  const int* keys = which ? dst : src;
  int lo = range * RANGE_NODES;
  for (int i = threadIdx.x; i < HWORDS; i += 256) h[i] = 0;
  __syncthreads();
  int per = (nkeys + HCHUNKS - 1) / HCHUNKS;
  int beg = chunk * per;
  int end = min(beg + per, nkeys);
  for (int i = beg + threadIdx.x; i < end; i += 256) {
    int k = keys[i] - lo;
    if ((unsigned)k < (unsigned)RANGE_NODES)
      atomicAdd(&h[k >> 2], 1u << ((k & 3) * 8));
  }
  __syncthreads();
  unsigned int* outp = partials + (size_t)blockIdx.x * HWORDS;
  for (int i = threadIdx.x; i < HWORDS; i += 256) outp[i] = h[i];
}

// ---------------------------------------------------------------------------
// Sum 64 chunk-partials per word, unpack bytes -> sn / dn / ideg.
// ---------------------------------------------------------------------------
__global__ __launch_bounds__(256) void reduce_norm_kernel(
    const unsigned int* __restrict__ ps, const unsigned int* __restrict__ pd,
    float* __restrict__ sn, float* __restrict__ dn, int* __restrict__ ideg) {
  int w = blockIdx.x * 256 + threadIdx.x;
  if (w >= 2 * (N_NODES / 4)) return;
  int is_dst = (w >= N_NODES / 4);
  int lw = is_dst ? w - N_NODES / 4 : w;
  const unsigned int* p = is_dst ? pd : ps;
  int r = lw / HWORDS, wr = lw % HWORDS;
  const unsigned int* base = p + (size_t)(r * HCHUNKS) * HWORDS + wr;
  unsigned int s0 = 0, s1 = 0, s2 = 0, s3 = 0;
  for (int c = 0; c < HCHUNKS; ++c) {
    unsigned int v = base[(size_t)c * HWORDS];
    s0 += v & 255u; s1 += (v >> 8) & 255u; s2 += (v >> 16) & 255u; s3 += v >> 24;
  }
  unsigned int d[4] = {s0, s1, s2, s3};
  int n0 = r * RANGE_NODES + wr * 4;
#pragma unroll
  for (int j = 0; j < 4; ++j) {
    int n = n0 + j;
    float f = (d[j] > 0) ? rsqrtf((float)d[j]) : 0.0f;
    if (is_dst) { dn[n] = f; ideg[n] = (int)d[j]; }
    else        { sn[n] = f; }
  }
}

// ---------------------------------------------------------------------------
// xb[n][k] = bf16( x[n][k] * sn[n] )  — prescaled bf16 gather operand.
// ---------------------------------------------------------------------------
__global__ __launch_bounds__(256) void convert_prescale_kernel(
    const float* __restrict__ x, const float* __restrict__ sn,
    unsigned int* __restrict__ xb2, int nquads) {
  int i = blockIdx.x * 256 + threadIdx.x;
  if (i >= nquads) return;
  float s = sn[i >> 4];                       // node = (i*4)/64
  float4 v = ((const float4*)x)[i];
  __hip_bfloat162 a = __float22bfloat162_rn(make_float2(v.x * s, v.y * s));
  __hip_bfloat162 b = __float22bfloat162_rn(make_float2(v.z * s, v.w * s));
  unsigned int wa, wb;
  __builtin_memcpy(&wa, &a, 4);
  __builtin_memcpy(&wb, &b, 4);
  ((uint2*)xb2)[i] = make_uint2(wa, wb);
}

// ---------------------------------------------------------------------------
// Exclusive scan, 3-kernel classic (n = 100000, nb = 391).
// ---------------------------------------------------------------------------
__global__ __launch_bounds__(SCAN_B) void scan_block_kernel(
    const int* __restrict__ in, int* __restrict__ out,
    int* __restrict__ bsum, int n) {
  __shared__ int s[SCAN_B];
  int t = threadIdx.x;
  int i = blockIdx.x * SCAN_B + t;
  int v = (i < n) ? in[i] : 0;
  s[t] = v;
  __syncthreads();
  for (int off = 1; off < SCAN_B; off <<= 1) {
    int add = (t >= off) ? s[t - off] : 0;
    __syncthreads();
    s[t] += add;
    __syncthreads();
  }
  if (i < n) out[i] = s[t] - v;
  if (t == SCAN_B - 1) bsum[blockIdx.x] = s[t];
}

__global__ __launch_bounds__(512) void scan_top_kernel(
    int* __restrict__ bsum, int nb) {
  __shared__ int s[512];
  int t = threadIdx.x;
  int v = (t < nb) ? bsum[t] : 0;
  s[t] = v;
  __syncthreads();
  for (int off = 1; off < 512; off <<= 1) {
    int add = (t >= off) ? s[t - off] : 0;
    __syncthreads();
    s[t] += add;
    __syncthreads();
  }
  if (t < nb) bsum[t] = s[t] - v;
}

__global__ __launch_bounds__(256) void scan_add_kernel(
    int* __restrict__ out, const int* __restrict__ bsum, int n, int total) {
  int i = blockIdx.x * blockDim.x + threadIdx.x;
  if (i < n) out[i] += bsum[i / SCAN_B];
  if (i == 0) out[n] = total;
}

// ---------------------------------------------------------------------------
// Partition edges into NBINS dst-bins.
// ---------------------------------------------------------------------------
__global__ __launch_bounds__(256) void bin_scatter_kernel(
    const int* __restrict__ src, const int* __restrict__ dst,
    const int* __restrict__ offsets, int* __restrict__ bin_cursor,
    int2* __restrict__ binned, int E) {
  __shared__ int cnt[NBINS];
  __shared__ int base[NBINS];
  int t = threadIdx.x;
  for (int i = t; i < NBINS; i += 256) cnt[i] = 0;
  __syncthreads();
  int per = (E + SCHUNKS - 1) / SCHUNKS;
  int beg = blockIdx.x * per;
  int end = min(beg + per, E);
  for (int i = beg + t; i < end; i += 256)
    atomicAdd(&cnt[dst[i] >> 9], 1);
  __syncthreads();
  for (int i = t; i < NBINS; i += 256) {
    base[i] = offsets[i << 9] + atomicAdd(&bin_cursor[i], cnt[i]);
    cnt[i] = 0;
  }
  __syncthreads();
  for (int i = beg + t; i < end; i += 256) {
    int s = src[i], d = dst[i];
    int b = d >> 9;
    int r = atomicAdd(&cnt[b], 1);
    binned[base[b] + r] = make_int2(s, d);
  }
}

// ---------------------------------------------------------------------------
// CSR fill, one block per bin.
// ---------------------------------------------------------------------------
__global__ __launch_bounds__(256) void fill_binned_kernel(
    const int2* __restrict__ binned, const int* __restrict__ offsets,
    int* __restrict__ csr_src) {
  __shared__ int cur[BINSZ];
  __shared__ int offs[BINSZ];
  int b = blockIdx.x;
  int t = threadIdx.x;
  int lo = b << 9;
  for (int i = t; i < BINSZ; i += 256) {
    cur[i] = 0;
    offs[i] = offsets[min(lo + i, N_NODES)];
  }
  __syncthreads();
  int w0 = offsets[lo];
  int w1 = offsets[min(lo + BINSZ, N_NODES)];
  for (int e = w0 + t; e < w1; e += 256) {
    int2 sd = binned[e];
    int r = atomicAdd(&cur[sd.y - lo], 1);
    csr_src[offs[sd.y - lo] + r] = sd.x;
  }
}

// ---------------------------------------------------------------------------
// Fused layer v7: 512-thread blocks (8 waves), wave per 16-node batch.
//   v5/v6 diagnosis: LDS pool for co-residency is effectively 64 KB/CU ->
//   32 KB/block pinned us at 2 blocks = 8 waves/CU (23% occ), gather BW
//   tracks resident waves (1.3-1.5 TB/s vs 2.0 at 40% occ).
//   Fix: LDS/block = Wfrag 16 KiB (shared by 8 waves) + 256 B/wave row
//   bounce buffer = 18 KiB -> 3 blocks/CU = 24 waves (75% cap).
//   Per node: lanes<16 write ONE float4 (f32 row, x dn); the node's 4 owner
//   lanes ((lane&15)==ni) read back 16 features as 4 x float4 -> registers.
//   Hi/lo bf16 conversion once per batch, all 64 lanes parallel.
//   Proven verbatim: gather loop, W-frag staging, 24-MFMA pattern, epilogue.
// ---------------------------------------------------------------------------
__device__ __forceinline__ float bf_lo(unsigned int u) {
  unsigned int x = u << 16; float f; __builtin_memcpy(&f, &x, 4); return f;
}
__device__ __forceinline__ float bf_hi(unsigned int u) {
  unsigned int x = u & 0xffff0000u; float f; __builtin_memcpy(&f, &x, 4); return f;
}
__device__ __forceinline__ unsigned short bf16bits(float f) {
  __hip_bfloat16 h = __float2bfloat16(f);
  unsigned short u; __builtin_memcpy(&u, &h, 2); return u;
}

template <bool PRESCALE, typename OUT_T>
__device__ __forceinline__ void epilogue_nt(
    float4v acc, float bv, int nb16, int kq, int lane, float snb,
    OUT_T* __restrict__ out, int nt) {
  int col = nt * 16 + (lane & 15);
#pragma unroll
  for (int r = 0; r < 4; ++r) {
    int node = nb16 + kq * 4 + r;          // C/D row = (lane>>4)*4 + reg
    float o = fmaxf(acc[r] + bv, 0.0f);
    if (PRESCALE) {
      o = o * __shfl(snb, kq * 4 + r);
      out[(long)node * DIM + col] = (OUT_T)__float2bfloat16(o);
    } else {
      out[(long)node * DIM + col] = (OUT_T)o;
    }
  }
}

template <bool PRESCALE, typename OUT_T>
__global__ __launch_bounds__(512, 6) void fused_layer_kernel(
    const __hip_bfloat16* __restrict__ xb, const int* __restrict__ csr_src,
    const int* __restrict__ offsets, const float* __restrict__ sn,
    const float* __restrict__ dn, const float* __restrict__ W,
    const float* __restrict__ bias, OUT_T* __restrict__ out, int N) {
  // W B-fragments: [hl][ntile][ktile][lane][8 bf16] = 16 KiB (8 waves share)
  __shared__ __align__(16) short Wfrag[2][4][2][64][8];
  // One-row bounce buffer per wave-slot: 64 f32 = 256 B x 8 = 2 KiB
  __shared__ __align__(16) float rowS[8][DIM];

  int t = threadIdx.x;
  int lane = t & 63;
  int wslot = t >> 6;          // 0..7
  int g = lane >> 4;           // edge sub-slot / MFMA k-group 0..3
  int q = lane & 15;           // feature quad; also node-owner id r

  // --- stage W as hi/lo bf16 B-fragments (once per block, proven layout) ---
  for (int e = t; e < 1024; e += 512) {
    int lidx = e & 63;
    int f = e >> 6;                       // 0..15
    int ktv = f & 1, ntv = (f >> 1) & 3, hl = f >> 3;
#pragma unroll
    for (int j = 0; j < 8; ++j) {
      int k = ktv * 32 + (lidx >> 4) * 8 + j;   // consecutive-K lane layout
      int c = ntv * 16 + (lidx & 15);
      float w = W[k * DIM + c];
      unsigned short hb = bf16bits(w);
      if (hl == 0) {
        Wfrag[0][ntv][ktv][lidx][j] = (short)hb;
      } else {
        unsigned int hx = (unsigned int)hb << 16;
        float hf; __builtin_memcpy(&hf, &hx, 4);
        Wfrag[1][ntv][ktv][lidx][j] = (short)bf16bits(w - hf);
      }
    }
  }
  __syncthreads();

  float bias_nt[4];
#pragma unroll
  for (int nt = 0; nt < 4; ++nt) bias_nt[nt] = bias[nt * 16 + (lane & 15)];

  const uint2* __restrict__ xr = (const uint2*)xb;   // one row = 16 uint2
  const float4* __restrict__ rrd = (const float4*)&rowS[wslot][0];

  int nwaves = gridDim.x * 8;
  for (int nb = blockIdx.x * 8 + wslot; nb < NBATCH; nb += nwaves) {
    int nb16 = nb * 16;
    // batch-wide CSR offsets (lanes 0..16) + per-node norms via lane index
    int offv = offsets[nb16 + min(lane, 16)];
    float dnv = dn[nb16 + q];
    float snb = PRESCALE ? sn[nb16 + q] : 0.0f;

    float fv[16];   // this lane's A-slice: feats {8g..8g+7, 32+8g..+7} of node q

    // ---- gather 16 nodes (proven structure) ----
    for (int ni = 0; ni < 16; ++ni) {
      int beg = __shfl(offv, ni);
      int end = __shfl(offv, ni + 1);
      float a0 = 0.f, a1 = 0.f, a2 = 0.f, a3 = 0.f;
      for (int base = beg; base < end; base += 16) {
        int j0 = base + g;
        int jm = end - 1;
        bool p0 = j0 < end, p1 = j0 + 4 < end, p2 = j0 + 8 < end,
             p3 = j0 + 12 < end;
        int s0 = csr_src[min(j0, jm)];
        int s1 = csr_src[min(j0 + 4, jm)];
        int s2 = csr_src[min(j0 + 8, jm)];
        int s3 = csr_src[min(j0 + 12, jm)];
        uint2 v0 = make_uint2(0u, 0u), v1 = v0, v2 = v0, v3 = v0;
        if (p0) v0 = xr[(size_t)s0 * 16 + q];
        if (p1) v1 = xr[(size_t)s1 * 16 + q];
        if (p2) v2 = xr[(size_t)s2 * 16 + q];
        if (p3) v3 = xr[(size_t)s3 * 16 + q];
        a0 += bf_lo(v0.x); a1 += bf_hi(v0.x); a2 += bf_lo(v0.y); a3 += bf_hi(v0.y);
        a0 += bf_lo(v1.x); a1 += bf_hi(v1.x); a2 += bf_lo(v1.y); a3 += bf_hi(v1.y);
        a0 += bf_lo(v2.x); a1 += bf_hi(v2.x); a2 += bf_lo(v2.y); a3 += bf_hi(v2.y);
        a0 += bf_lo(v3.x); a1 += bf_hi(v3.x); a2 += bf_lo(v3.y); a3 += bf_hi(v3.y);
      }
      a0 += __shfl_xor(a0, 16); a1 += __shfl_xor(a1, 16);
      a2 += __shfl_xor(a2, 16); a3 += __shfl_xor(a3, 16);
      a0 += __shfl_xor(a0, 32); a1 += __shfl_xor(a1, 32);
      a2 += __shfl_xor(a2, 32); a3 += __shfl_xor(a3, 32);

      float dnw = __shfl(dnv, ni);
      if (lane < 16) {
        ((float4*)&rowS[wslot][0])[q] =
            make_float4(a0 * dnw, a1 * dnw, a2 * dnw, a3 * dnw);
      }
      // same-wave LDS write -> read: ordered by lgkmcnt, no barrier needed.
      // Node ni's 4 owner lanes pull their A-slice into registers.
      if (q == ni) {
        float4 x0 = rrd[2 * g];          // feats 8g..8g+3
        float4 x1 = rrd[2 * g + 1];      // feats 8g+4..8g+7
        float4 x2 = rrd[8 + 2 * g];      // feats 32+8g..+3
        float4 x3 = rrd[8 + 2 * g + 1];  // feats 32+8g+4..+7
        fv[0] = x0.x;  fv[1] = x0.y;  fv[2] = x0.z;  fv[3] = x0.w;
        fv[4] = x1.x;  fv[5] = x1.y;  fv[6] = x1.z;  fv[7] = x1.w;
        fv[8] = x2.x;  fv[9] = x2.y;  fv[10] = x2.z; fv[11] = x2.w;
        fv[12] = x3.x; fv[13] = x3.y; fv[14] = x3.z; fv[15] = x3.w;
      }
    }

    // ---- convert fv -> hi/lo bf16 A-fragments (all 64 lanes parallel) ----
    union { unsigned int w[4]; short8v v; } Uh0, Ul0, Uh1, Ul1;
#pragma unroll
    for (int p = 0; p < 4; ++p) {
      unsigned int u0, u1, u2, u3;
      __builtin_memcpy(&u0, &fv[2 * p], 4);
      __builtin_memcpy(&u1, &fv[2 * p + 1], 4);
      __builtin_memcpy(&u2, &fv[8 + 2 * p], 4);
      __builtin_memcpy(&u3, &fv[8 + 2 * p + 1], 4);
      unsigned int h0 = u0 & 0xffff0000u, h1 = u1 & 0xffff0000u;
      unsigned int h2 = u2 & 0xffff0000u, h3 = u3 & 0xffff0000u;
      Uh0.w[p] = (h0 >> 16) | h1;
      Uh1.w[p] = (h2 >> 16) | h3;
      float hf0, hf1, hf2, hf3;
      __builtin_memcpy(&hf0, &h0, 4); __builtin_memcpy(&hf1, &h1, 4);
      __builtin_memcpy(&hf2, &h2, 4); __builtin_memcpy(&hf3, &h3, 4);
      __hip_bfloat162 lo01 = __float22bfloat162_rn(
          make_float2(fv[2 * p] - hf0, fv[2 * p + 1] - hf1));
      __hip_bfloat162 lo23 = __float22bfloat162_rn(
          make_float2(fv[8 + 2 * p] - hf2, fv[8 + 2 * p + 1] - hf3));
      __builtin_memcpy(&Ul0.w[p], &lo01, 4);
      __builtin_memcpy(&Ul1.w[p], &lo23, 4);
    }

    // ---- 24 x mfma_f32_16x16x32_bf16 (proven pattern) ----
    float4v acc0 = {0.f, 0.f, 0.f, 0.f}, acc1 = acc0, acc2 = acc0, acc3 = acc0;
#pragma unroll
    for (int kt = 0; kt < 2; ++kt) {
      short8v ahi = kt ? Uh1.v : Uh0.v;
      short8v alo = kt ? Ul1.v : Ul0.v;
#define PROJ_NT(NT, ACC)                                                      \
      {                                                                       \
        short8v bh = *(short8v*)&Wfrag[0][NT][kt][lane][0];                   \
        short8v bl = *(short8v*)&Wfrag[1][NT][kt][lane][0];                   \
        ACC = __builtin_amdgcn_mfma_f32_16x16x32_bf16(ahi, bh, ACC, 0, 0, 0); \
        ACC = __builtin_amdgcn_mfma_f32_16x16x32_bf16(alo, bh, ACC, 0, 0, 0); \
        ACC = __builtin_amdgcn_mfma_f32_16x16x32_bf16(ahi, bl, ACC, 0, 0, 0); \
      }
      PROJ_NT(0, acc0)
      PROJ_NT(1, acc1)
      PROJ_NT(2, acc2)
      PROJ_NT(3, acc3)
#undef PROJ_NT
    }

    float snbv = PRESCALE ? snb : 0.0f;
    epilogue_nt<PRESCALE, OUT_T>(acc0, bias_nt[0], nb16, g, lane, snbv, out, 0);
    epilogue_nt<PRESCALE, OUT_T>(acc1, bias_nt[1], nb16, g, lane, snbv, out, 1);
    epilogue_nt<PRESCALE, OUT_T>(acc2, bias_nt[2], nb16, g, lane, snbv, out, 2);
    epilogue_nt<PRESCALE, OUT_T>(acc3, bias_nt[3], nb16, g, lane, snbv, out, 3);
  }
}

extern "C" void kernel_launch(void* const* d_in, const int* in_sizes, int n_in,
                              void* d_out, int out_size, void* d_ws, size_t ws_size,
                              hipStream_t stream) {
  const float* x        = (const float*)d_in[0];
  const int*   edge_src = (const int*)d_in[1];
  const int*   edge_dst = (const int*)d_in[2];
  const float* W1       = (const float*)d_in[3];
  const float* b1       = (const float*)d_in[4];
  const float* W2       = (const float*)d_in[5];
  const float* b2       = (const float*)d_in[6];
  float* out = (float*)d_out;

  const int E = in_sizes[1];
  const int N = N_NODES;
  const int NB = (N + SCAN_B - 1) / SCAN_B;   // 391

  // Workspace (4B units), ~33.6 MB total. regionB time-shared:
  //   partials (hist..reduce) -> binned (bin_scatter..fill) -> h1b (layers)
  float* sn         = (float*)d_ws;                  // N
  float* dn         = sn + N;                        // N
  int*   ideg       = (int*)(dn + N);                // N
  int*   offsets    = ideg + N;                      // N+1
  int*   bsum       = offsets + (N + 1);             // 512
  int*   bin_cursor = bsum + 512;                    // 256
  int*   csr_src    = bin_cursor + 256;              // E
  unsigned int* xb_raw = (unsigned int*)(csr_src + E);       // N*DIM/2 (12.8MB)
  unsigned int* regionB = xb_raw + (size_t)N * DIM / 2;      // 12.8MB
  unsigned int* partials = regionB;                          // 256*HWORDS
  int2*  binned   = (int2*)regionB;                  // E int2
  __hip_bfloat16* xb  = (__hip_bfloat16*)xb_raw;
  __hip_bfloat16* h1b = (__hip_bfloat16*)regionB;

  hipMemsetAsync(bin_cursor, 0, 256 * sizeof(int), stream);

  // --- degrees + norms (no global atomics) ---
  hist_kernel<<<256, 256, 0, stream>>>(edge_src, edge_dst, E, partials);
  reduce_norm_kernel<<<(2 * (N / 4) + 255) / 256, 256, 0, stream>>>(
      partials, partials + (size_t)128 * HWORDS, sn, dn, ideg);

  // --- prescaled bf16 copy of x ---
  {
    int nquads = N * DIM / 4;
    convert_prescale_kernel<<<(nquads + 255) / 256, 256, 0, stream>>>(
        x, sn, xb_raw, nquads);
  }

  // --- offsets = exclusive scan of in-degree ---
  scan_block_kernel<<<NB, SCAN_B, 0, stream>>>(ideg, offsets, bsum, N);
  scan_top_kernel<<<1, 512, 0, stream>>>(bsum, NB);
  scan_add_kernel<<<(N + 255) / 256, 256, 0, stream>>>(offsets, bsum, N, E);

  // --- binned CSR build (overwrites partials region — dead after reduce) ---
  bin_scatter_kernel<<<SCHUNKS, 256, 0, stream>>>(edge_src, edge_dst, offsets,
                                                  bin_cursor, binned, E);
  fill_binned_kernel<<<NBINS, 256, 0, stream>>>(binned, offsets, csr_src);

  const int fb = 768;   // 3 blocks/CU (18KB LDS under 64KB pool), 24 waves/CU

  // --- layer 1: xb -> h1b (bf16, prescaled by sn; overwrites binned) ---
  fused_layer_kernel<true, __hip_bfloat16><<<fb, 512, 0, stream>>>(
      xb, csr_src, offsets, sn, dn, W1, b1, h1b, N);

  // --- layer 2: h1b -> out (fp32) ---
  fused_layer_kernel<false, float><<<fb, 512, 0, stream>>>(
      h1b, csr_src, offsets, sn, dn, W2, b2, out, N);
}

// Round 7
// 265.426 us; speedup vs baseline: 1.2520x; 1.1859x over previous
//
#include <hip/hip_runtime.h>
#include <hip/hip_bf16.h>

#define N_NODES 100000
#define DIM 64
#define SCAN_B 256

#define RANGE_NODES 50000   // node-range per histogram block (50KB LDS bytes)
#define HWORDS 12500        // RANGE_NODES/4 packed-byte words
#define HCHUNKS 64          // edge chunks per (array,range)
#define SCHUNKS 128         // edge chunks for bin scatter
#define BINSZ 512           // dst nodes per bin
#define NBINS 196           // ceil(N_NODES/BINSZ)

#define NBATCH 6250         // 100000 / 16 node-batches (exact)

typedef __attribute__((ext_vector_type(8))) short short8v;
typedef __attribute__((ext_vector_type(4))) float float4v;

// ---------------------------------------------------------------------------
// Packed-byte histogram, one launch: blocks [0,128) = src, [128,256) = dst.
// ---------------------------------------------------------------------------
__global__ __launch_bounds__(256) void hist_kernel(
    const int* __restrict__ src, const int* __restrict__ dst, int nkeys,
    unsigned int* __restrict__ partials) {
  __shared__ unsigned int h[HWORDS];
  int which = blockIdx.x >> 7;             // 0 = src, 1 = dst
  int local = blockIdx.x & 127;
  int range = local >> 6;
  int chunk = local & 63;
  const int* keys = which ? dst : src;
  int lo = range * RANGE_NODES;
  for (int i = threadIdx.x; i < HWORDS; i += 256) h[i] = 0;
  __syncthreads();
  int per = (nkeys + HCHUNKS - 1) / HCHUNKS;
  int beg = chunk * per;
  int end = min(beg + per, nkeys);
  for (int i = beg + threadIdx.x; i < end; i += 256) {
    int k = keys[i] - lo;
    if ((unsigned)k < (unsigned)RANGE_NODES)
      atomicAdd(&h[k >> 2], 1u << ((k & 3) * 8));
  }
  __syncthreads();
  unsigned int* outp = partials + (size_t)blockIdx.x * HWORDS;
  for (int i = threadIdx.x; i < HWORDS; i += 256) outp[i] = h[i];
}

// ---------------------------------------------------------------------------
// Sum 64 chunk-partials per word, unpack bytes -> sn / dn / ideg.
// ---------------------------------------------------------------------------
__global__ __launch_bounds__(256) void reduce_norm_kernel(
    const unsigned int* __restrict__ ps, const unsigned int* __restrict__ pd,
    float* __restrict__ sn, float* __restrict__ dn, int* __restrict__ ideg) {
  int w = blockIdx.x * 256 + threadIdx.x;
  if (w >= 2 * (N_NODES / 4)) return;
  int is_dst = (w >= N_NODES / 4);
  int lw = is_dst ? w - N_NODES / 4 : w;
  const unsigned int* p = is_dst ? pd : ps;
  int r = lw / HWORDS, wr = lw % HWORDS;
  const unsigned int* base = p + (size_t)(r * HCHUNKS) * HWORDS + wr;
  unsigned int s0 = 0, s1 = 0, s2 = 0, s3 = 0;
  for (int c = 0; c < HCHUNKS; ++c) {
    unsigned int v = base[(size_t)c * HWORDS];
    s0 += v & 255u; s1 += (v >> 8) & 255u; s2 += (v >> 16) & 255u; s3 += v >> 24;
  }
  unsigned int d[4] = {s0, s1, s2, s3};
  int n0 = r * RANGE_NODES + wr * 4;
#pragma unroll
  for (int j = 0; j < 4; ++j) {
    int n = n0 + j;
    float f = (d[j] > 0) ? rsqrtf((float)d[j]) : 0.0f;
    if (is_dst) { dn[n] = f; ideg[n] = (int)d[j]; }
    else        { sn[n] = f; }
  }
}

// ---------------------------------------------------------------------------
// xb[n][k] = bf16( x[n][k] * sn[n] )  — prescaled bf16 gather operand.
// ---------------------------------------------------------------------------
__global__ __launch_bounds__(256) void convert_prescale_kernel(
    const float* __restrict__ x, const float* __restrict__ sn,
    unsigned int* __restrict__ xb2, int nquads) {
  int i = blockIdx.x * 256 + threadIdx.x;
  if (i >= nquads) return;
  float s = sn[i >> 4];                       // node = (i*4)/64
  float4 v = ((const float4*)x)[i];
  __hip_bfloat162 a = __float22bfloat162_rn(make_float2(v.x * s, v.y * s));
  __hip_bfloat162 b = __float22bfloat162_rn(make_float2(v.z * s, v.w * s));
  unsigned int wa, wb;
  __builtin_memcpy(&wa, &a, 4);
  __builtin_memcpy(&wb, &b, 4);
  ((uint2*)xb2)[i] = make_uint2(wa, wb);
}

// ---------------------------------------------------------------------------
// Exclusive scan, 3-kernel classic (n = 100000, nb = 391).
// ---------------------------------------------------------------------------
__global__ __launch_bounds__(SCAN_B) void scan_block_kernel(
    const int* __restrict__ in, int* __restrict__ out,
    int* __restrict__ bsum, int n) {
  __shared__ int s[SCAN_B];
  int t = threadIdx.x;
  int i = blockIdx.x * SCAN_B + t;
  int v = (i < n) ? in[i] : 0;
  s[t] = v;
  __syncthreads();
  for (int off = 1; off < SCAN_B; off <<= 1) {
    int add = (t >= off) ? s[t - off] : 0;
    __syncthreads();
    s[t] += add;
    __syncthreads();
  }
  if (i < n) out[i] = s[t] - v;
  if (t == SCAN_B - 1) bsum[blockIdx.x] = s[t];
}

__global__ __launch_bounds__(512) void scan_top_kernel(
    int* __restrict__ bsum, int nb) {
  __shared__ int s[512];
  int t = threadIdx.x;
  int v = (t < nb) ? bsum[t] : 0;
  s[t] = v;
  __syncthreads();
  for (int off = 1; off < 512; off <<= 1) {
    int add = (t >= off) ? s[t - off] : 0;
    __syncthreads();
    s[t] += add;
    __syncthreads();
  }
  if (t < nb) bsum[t] = s[t] - v;
}

__global__ __launch_bounds__(256) void scan_add_kernel(
    int* __restrict__ out, const int* __restrict__ bsum, int n, int total) {
  int i = blockIdx.x * blockDim.x + threadIdx.x;
  if (i < n) out[i] += bsum[i / SCAN_B];
  if (i == 0) out[n] = total;
}

// ---------------------------------------------------------------------------
// Partition edges into NBINS dst-bins.
// ---------------------------------------------------------------------------
__global__ __launch_bounds__(256) void bin_scatter_kernel(
    const int* __restrict__ src, const int* __restrict__ dst,
    const int* __restrict__ offsets, int* __restrict__ bin_cursor,
    int2* __restrict__ binned, int E) {
  __shared__ int cnt[NBINS];
  __shared__ int base[NBINS];
  int t = threadIdx.x;
  for (int i = t; i < NBINS; i += 256) cnt[i] = 0;
  __syncthreads();
  int per = (E + SCHUNKS - 1) / SCHUNKS;
  int beg = blockIdx.x * per;
  int end = min(beg + per, E);
  for (int i = beg + t; i < end; i += 256)
    atomicAdd(&cnt[dst[i] >> 9], 1);
  __syncthreads();
  for (int i = t; i < NBINS; i += 256) {
    base[i] = offsets[i << 9] + atomicAdd(&bin_cursor[i], cnt[i]);
    cnt[i] = 0;
  }
  __syncthreads();
  for (int i = beg + t; i < end; i += 256) {
    int s = src[i], d = dst[i];
    int b = d >> 9;
    int r = atomicAdd(&cnt[b], 1);
    binned[base[b] + r] = make_int2(s, d);
  }
}

// ---------------------------------------------------------------------------
// CSR fill, one block per bin.
// ---------------------------------------------------------------------------
__global__ __launch_bounds__(256) void fill_binned_kernel(
    const int2* __restrict__ binned, const int* __restrict__ offsets,
    int* __restrict__ csr_src) {
  __shared__ int cur[BINSZ];
  __shared__ int offs[BINSZ];
  int b = blockIdx.x;
  int t = threadIdx.x;
  int lo = b << 9;
  for (int i = t; i < BINSZ; i += 256) {
    cur[i] = 0;
    offs[i] = offsets[min(lo + i, N_NODES)];
  }
  __syncthreads();
  int w0 = offsets[lo];
  int w1 = offsets[min(lo + BINSZ, N_NODES)];
  for (int e = w0 + t; e < w1; e += 256) {
    int2 sd = binned[e];
    int r = atomicAdd(&cur[sd.y - lo], 1);
    csr_src[offs[sd.y - lo] + r] = sd.x;
  }
}

// ---------------------------------------------------------------------------
// bf16 helpers (proven numerics).
// ---------------------------------------------------------------------------
__device__ __forceinline__ float bf_lo(unsigned int u) {
  unsigned int x = u << 16; float f; __builtin_memcpy(&f, &x, 4); return f;
}
__device__ __forceinline__ float bf_hi(unsigned int u) {
  unsigned int x = u & 0xffff0000u; float f; __builtin_memcpy(&f, &x, 4); return f;
}
__device__ __forceinline__ unsigned short bf16bits(float f) {
  __hip_bfloat16 h = __float2bfloat16(f);
  unsigned short u; __builtin_memcpy(&u, &h, 2); return u;
}
// (x,y) f32 -> packed hi bf16x2 (truncated) + packed lo bf16x2 (residual, RNE)
__device__ __forceinline__ void cvt_pair_hl(float x, float y,
                                            unsigned int& hi, unsigned int& lo) {
  unsigned int u0, u1;
  __builtin_memcpy(&u0, &x, 4);
  __builtin_memcpy(&u1, &y, 4);
  unsigned int h0 = u0 & 0xffff0000u, h1 = u1 & 0xffff0000u;
  hi = (h0 >> 16) | h1;
  float hf0, hf1;
  __builtin_memcpy(&hf0, &h0, 4);
  __builtin_memcpy(&hf1, &h1, 4);
  __hip_bfloat162 l2 = __float22bfloat162_rn(make_float2(x - hf0, y - hf1));
  __builtin_memcpy(&lo, &l2, 4);
}

// ---------------------------------------------------------------------------
// Pre-stage W as hi/lo bf16 B-fragments into GLOBAL (16 KiB per table).
// Layout: entry e = ((hl*4 + nt)*2 + kt)*64 + lane, 8 shorts each.
// k = kt*32 + (lane>>4)*8 + j, c = nt*16 + (lane&15)  (proven layout).
// Block 0 -> W1 table, block 1 -> W2 table.
// ---------------------------------------------------------------------------
__global__ __launch_bounds__(256) void stage_wfrag_kernel(
    const float* __restrict__ W1, const float* __restrict__ W2,
    short* __restrict__ Wg) {
  const float* W = blockIdx.x ? W2 : W1;
  short* outp = Wg + blockIdx.x * 8192;
  int t = threadIdx.x;
  for (int e = t; e < 1024; e += 256) {
    int lidx = e & 63;
    int f = e >> 6;                       // 0..15
    int ktv = f & 1, ntv = (f >> 1) & 3, hl = f >> 3;
#pragma unroll
    for (int j = 0; j < 8; ++j) {
      int k = ktv * 32 + (lidx >> 4) * 8 + j;
      int c = ntv * 16 + (lidx & 15);
      float w = W[k * DIM + c];
      unsigned short hb = bf16bits(w);
      short val;
      if (hl == 0) {
        val = (short)hb;
      } else {
        unsigned int hx = (unsigned int)hb << 16;
        float hf; __builtin_memcpy(&hf, &hx, 4);
        val = (short)bf16bits(w - hf);
      }
      outp[e * 8 + j] = val;
    }
  }
}

// ---------------------------------------------------------------------------
// Fused layer v8: 256-thr blocks (4 waves), wave per 16-node batch.
//   v7 diagnosis: predicated fv[16] register capture -> scratch (WRITE_SIZE
//   94 MB, VGPR=40); scratch traffic ~45% of bytes + residency cap.
//   Fixes:
//   - A staging in LDS [4][16][64] f32 (16 KiB/block) — static addressing,
//     NO per-lane arrays, no predicated reg fill -> scratch impossible.
//     XOR swizzle (off ^ ((row&15)<<4)) on BOTH write and read (bijective,
//     2-way max = free).
//   - Wfrag OUT of LDS: pre-staged hi/lo bf16 B-frags in global (L1-resident
//     16 KiB table); 16 x 16 B loads per batch. asm memory clobber per batch
//     stops hoisting into a 64-reg table (the v2-v4 allocator fight).
//   - No __syncthreads anywhere; 4 blocks/CU under 64 KB LDS pool.
//   Proven verbatim: gather loop, frag layouts, 24-MFMA hi/lo pattern,
//   epilogue mapping.
// ---------------------------------------------------------------------------
template <bool PRESCALE, typename OUT_T>
__device__ __forceinline__ void epilogue_nt(
    float4v acc, float bv, int nb16, int kq, int lane, float snb,
    OUT_T* __restrict__ out, int nt) {
  int col = nt * 16 + (lane & 15);
#pragma unroll
  for (int r = 0; r < 4; ++r) {
    int node = nb16 + kq * 4 + r;          // C/D row = (lane>>4)*4 + reg
    float o = fmaxf(acc[r] + bv, 0.0f);
    if (PRESCALE) {
      o = o * __shfl(snb, kq * 4 + r);
      out[(long)node * DIM + col] = (OUT_T)__float2bfloat16(o);
    } else {
      out[(long)node * DIM + col] = (OUT_T)o;
    }
  }
}

template <bool PRESCALE, typename OUT_T>
__global__ __launch_bounds__(256, 4) void fused_layer_kernel(
    const __hip_bfloat16* __restrict__ xb, const int* __restrict__ csr_src,
    const int* __restrict__ offsets, const float* __restrict__ sn,
    const float* __restrict__ dn, const short* __restrict__ Wg,
    const float* __restrict__ bias, OUT_T* __restrict__ out, int N) {
  __shared__ __align__(16) float Astage[4][16][64];   // 16 KiB

  int t = threadIdx.x;
  int lane = t & 63;
  int wslot = t >> 6;          // 0..3
  int g = lane >> 4;           // edge sub-slot / MFMA k-group 0..3
  int q = lane & 15;           // feature quad / A-row (node-in-batch)

  float bias_nt[4];
#pragma unroll
  for (int nt = 0; nt < 4; ++nt) bias_nt[nt] = bias[nt * 16 + q];

  const uint2* __restrict__ xr = (const uint2*)xb;   // one row = 16 uint2
  const short8v* __restrict__ wfrag = (const short8v*)Wg;
  char* abase = (char*)&Astage[wslot][0][0];         // 256 B per node row

  int nwaves = gridDim.x * 4;
  for (int nb = blockIdx.x * 4 + wslot; nb < NBATCH; nb += nwaves) {
    asm volatile("" ::: "memory");   // no cross-batch hoist of W-frag loads
    int nb16 = nb * 16;
    int offv = offsets[nb16 + min(lane, 16)];
    float dnv = dn[nb16 + q];
    float snb = PRESCALE ? sn[nb16 + q] : 0.0f;

    // ---- gather 16 nodes (proven structure) ----
    for (int ni = 0; ni < 16; ++ni) {
      int beg = __shfl(offv, ni);
      int end = __shfl(offv, ni + 1);
      float a0 = 0.f, a1 = 0.f, a2 = 0.f, a3 = 0.f;
      for (int base = beg; base < end; base += 16) {
        int j0 = base + g;
        int jm = end - 1;
        bool p0 = j0 < end, p1 = j0 + 4 < end, p2 = j0 + 8 < end,
             p3 = j0 + 12 < end;
        int s0 = csr_src[min(j0, jm)];
        int s1 = csr_src[min(j0 + 4, jm)];
        int s2 = csr_src[min(j0 + 8, jm)];
        int s3 = csr_src[min(j0 + 12, jm)];
        uint2 v0 = make_uint2(0u, 0u), v1 = v0, v2 = v0, v3 = v0;
        if (p0) v0 = xr[(size_t)s0 * 16 + q];
        if (p1) v1 = xr[(size_t)s1 * 16 + q];
        if (p2) v2 = xr[(size_t)s2 * 16 + q];
        if (p3) v3 = xr[(size_t)s3 * 16 + q];
        a0 += bf_lo(v0.x); a1 += bf_hi(v0.x); a2 += bf_lo(v0.y); a3 += bf_hi(v0.y);
        a0 += bf_lo(v1.x); a1 += bf_hi(v1.x); a2 += bf_lo(v1.y); a3 += bf_hi(v1.y);
        a0 += bf_lo(v2.x); a1 += bf_hi(v2.x); a2 += bf_lo(v2.y); a3 += bf_hi(v2.y);
        a0 += bf_lo(v3.x); a1 += bf_hi(v3.x); a2 += bf_lo(v3.y); a3 += bf_hi(v3.y);
      }
      a0 += __shfl_xor(a0, 16); a1 += __shfl_xor(a1, 16);
      a2 += __shfl_xor(a2, 16); a3 += __shfl_xor(a3, 16);
      a0 += __shfl_xor(a0, 32); a1 += __shfl_xor(a1, 32);
      a2 += __shfl_xor(a2, 32); a3 += __shfl_xor(a3, 32);

      float dnw = __shfl(dnv, ni);
      if (lane < 16) {
        // quad q of node ni at swizzled slot (both sides use same involution)
        int woff = ni * 256 + ((lane * 16) ^ ((ni & 15) << 4));
        *(float4*)(abase + woff) =
            make_float4(a0 * dnw, a1 * dnw, a2 * dnw, a3 * dnw);
      }
    }

    // ---- project: read A rows (same-wave LDS, lgkm-ordered), 24 MFMA ----
    float4v acc0 = {0.f, 0.f, 0.f, 0.f}, acc1 = acc0, acc2 = acc0, acc3 = acc0;
#pragma unroll
    for (int kt = 0; kt < 2; ++kt) {
      int o1 = kt * 128 + g * 32;     // feats kt*32+8g.. of node q
      float4 fa = *(const float4*)(abase + q * 256 + (o1 ^ (q << 4)));
      float4 fb = *(const float4*)(abase + q * 256 + ((o1 + 16) ^ (q << 4)));
      union { unsigned int w[4]; short8v v; } Uh, Ul;
      cvt_pair_hl(fa.x, fa.y, Uh.w[0], Ul.w[0]);
      cvt_pair_hl(fa.z, fa.w, Uh.w[1], Ul.w[1]);
      cvt_pair_hl(fb.x, fb.y, Uh.w[2], Ul.w[2]);
      cvt_pair_hl(fb.z, fb.w, Uh.w[3], Ul.w[3]);
      short8v ahi = Uh.v, alo = Ul.v;
#define PROJ_NT(NT, ACC)                                                      \
      {                                                                       \
        short8v bh = wfrag[(((NT) * 2) + kt) * 64 + lane];                    \
        short8v bl = wfrag[(((4 + (NT)) * 2) + kt) * 64 + lane];              \
        ACC = __builtin_amdgcn_mfma_f32_16x16x32_bf16(ahi, bh, ACC, 0, 0, 0); \
        ACC = __builtin_amdgcn_mfma_f32_16x16x32_bf16(alo, bh, ACC, 0, 0, 0); \
        ACC = __builtin_amdgcn_mfma_f32_16x16x32_bf16(ahi, bl, ACC, 0, 0, 0); \
      }
      PROJ_NT(0, acc0)
      PROJ_NT(1, acc1)
      PROJ_NT(2, acc2)
      PROJ_NT(3, acc3)
#undef PROJ_NT
    }

    float snbv = PRESCALE ? snb : 0.0f;
    epilogue_nt<PRESCALE, OUT_T>(acc0, bias_nt[0], nb16, g, lane, snbv, out, 0);
    epilogue_nt<PRESCALE, OUT_T>(acc1, bias_nt[1], nb16, g, lane, snbv, out, 1);
    epilogue_nt<PRESCALE, OUT_T>(acc2, bias_nt[2], nb16, g, lane, snbv, out, 2);
    epilogue_nt<PRESCALE, OUT_T>(acc3, bias_nt[3], nb16, g, lane, snbv, out, 3);
  }
}

extern "C" void kernel_launch(void* const* d_in, const int* in_sizes, int n_in,
                              void* d_out, int out_size, void* d_ws, size_t ws_size,
                              hipStream_t stream) {
  const float* x        = (const float*)d_in[0];
  const int*   edge_src = (const int*)d_in[1];
  const int*   edge_dst = (const int*)d_in[2];
  const float* W1       = (const float*)d_in[3];
  const float* b1       = (const float*)d_in[4];
  const float* W2       = (const float*)d_in[5];
  const float* b2       = (const float*)d_in[6];
  float* out = (float*)d_out;

  const int E = in_sizes[1];
  const int N = N_NODES;
  const int NB = (N + SCAN_B - 1) / SCAN_B;   // 391

  // Workspace (4B units), ~33.6 MB total. regionB time-shared:
  //   partials (hist..reduce) -> binned (bin_scatter..fill) -> h1b (layers)
  // ideg time-shared: degree counts (reduce..scan_block) -> W frag tables.
  float* sn         = (float*)d_ws;                  // N
  float* dn         = sn + N;                        // N
  int*   ideg       = (int*)(dn + N);                // N
  int*   offsets    = ideg + N;                      // N+1
  int*   bsum       = offsets + (N + 1);             // 512
  int*   bin_cursor = bsum + 512;                    // 256
  int*   csr_src    = bin_cursor + 256;              // E
  unsigned int* xb_raw = (unsigned int*)(csr_src + E);       // N*DIM/2 (12.8MB)
  unsigned int* regionB = xb_raw + (size_t)N * DIM / 2;      // 12.8MB
  unsigned int* partials = regionB;                          // 256*HWORDS
  int2*  binned   = (int2*)regionB;                  // E int2
  __hip_bfloat16* xb  = (__hip_bfloat16*)xb_raw;
  __hip_bfloat16* h1b = (__hip_bfloat16*)regionB;
  short* Wg = (short*)ideg;                          // 2 x 8192 shorts (32 KB)

  hipMemsetAsync(bin_cursor, 0, 256 * sizeof(int), stream);

  // --- degrees + norms (no global atomics) ---
  hist_kernel<<<256, 256, 0, stream>>>(edge_src, edge_dst, E, partials);
  reduce_norm_kernel<<<(2 * (N / 4) + 255) / 256, 256, 0, stream>>>(
      partials, partials + (size_t)128 * HWORDS, sn, dn, ideg);

  // --- prescaled bf16 copy of x ---
  {
    int nquads = N * DIM / 4;
    convert_prescale_kernel<<<(nquads + 255) / 256, 256, 0, stream>>>(
        x, sn, xb_raw, nquads);
  }

  // --- offsets = exclusive scan of in-degree ---
  scan_block_kernel<<<NB, SCAN_B, 0, stream>>>(ideg, offsets, bsum, N);
  // ideg dead after scan_block: overwrite with W fragment tables
  stage_wfrag_kernel<<<2, 256, 0, stream>>>(W1, W2, Wg);
  scan_top_kernel<<<1, 512, 0, stream>>>(bsum, NB);
  scan_add_kernel<<<(N + 255) / 256, 256, 0, stream>>>(offsets, bsum, N, E);

  // --- binned CSR build (overwrites partials region — dead after reduce) ---
  bin_scatter_kernel<<<SCHUNKS, 256, 0, stream>>>(edge_src, edge_dst, offsets,
                                                  bin_cursor, binned, E);
  fill_binned_kernel<<<NBINS, 256, 0, stream>>>(binned, offsets, csr_src);

  const int fb = 1563;   // one 16-node batch per wave (6252 waves >= 6250)

  // --- layer 1: xb -> h1b (bf16, prescaled by sn; overwrites binned) ---
  fused_layer_kernel<true, __hip_bfloat16><<<fb, 256, 0, stream>>>(
      xb, csr_src, offsets, sn, dn, Wg, b1, h1b, N);

  // --- layer 2: h1b -> out (fp32) ---
  fused_layer_kernel<false, float><<<fb, 256, 0, stream>>>(
      h1b, csr_src, offsets, sn, dn, Wg + 8192, b2, out, N);
}

// Round 8
// 264.349 us; speedup vs baseline: 1.2571x; 1.0041x over previous
//
#include <hip/hip_runtime.h>
#include <hip/hip_bf16.h>

#define N_NODES 100000
#define DIM 64
#define SCAN_B 256

#define RANGE_NODES 50000   // node-range per histogram block (50KB LDS bytes)
#define HWORDS 12500        // RANGE_NODES/4 packed-byte words
#define HCHUNKS 64          // edge chunks per (array,range)
#define SCHUNKS 128         // edge chunks for bin scatter
#define BINSZ 512           // dst nodes per bin
#define NBINS 196           // ceil(N_NODES/BINSZ)

#define NBATCH 6250         // 100000 / 16 node-batches (exact)

typedef __attribute__((ext_vector_type(8))) short short8v;
typedef __attribute__((ext_vector_type(4))) float float4v;

// ---------------------------------------------------------------------------
// Packed-byte histogram, one launch: blocks [0,128) = src, [128,256) = dst.
// ---------------------------------------------------------------------------
__global__ __launch_bounds__(256) void hist_kernel(
    const int* __restrict__ src, const int* __restrict__ dst, int nkeys,
    unsigned int* __restrict__ partials) {
  __shared__ unsigned int h[HWORDS];
  int which = blockIdx.x >> 7;             // 0 = src, 1 = dst
  int local = blockIdx.x & 127;
  int range = local >> 6;
  int chunk = local & 63;
  const int* keys = which ? dst : src;
  int lo = range * RANGE_NODES;
  for (int i = threadIdx.x; i < HWORDS; i += 256) h[i] = 0;
  __syncthreads();
  int per = (nkeys + HCHUNKS - 1) / HCHUNKS;
  int beg = chunk * per;
  int end = min(beg + per, nkeys);
  for (int i = beg + threadIdx.x; i < end; i += 256) {
    int k = keys[i] - lo;
    if ((unsigned)k < (unsigned)RANGE_NODES)
      atomicAdd(&h[k >> 2], 1u << ((k & 3) * 8));
  }
  __syncthreads();
  unsigned int* outp = partials + (size_t)blockIdx.x * HWORDS;
  for (int i = threadIdx.x; i < HWORDS; i += 256) outp[i] = h[i];
}

// ---------------------------------------------------------------------------
// Sum 64 chunk-partials per word, unpack bytes -> sn / dn / ideg.
// ---------------------------------------------------------------------------
__global__ __launch_bounds__(256) void reduce_norm_kernel(
    const unsigned int* __restrict__ ps, const unsigned int* __restrict__ pd,
    float* __restrict__ sn, float* __restrict__ dn, int* __restrict__ ideg) {
  int w = blockIdx.x * 256 + threadIdx.x;
  if (w >= 2 * (N_NODES / 4)) return;
  int is_dst = (w >= N_NODES / 4);
  int lw = is_dst ? w - N_NODES / 4 : w;
  const unsigned int* p = is_dst ? pd : ps;
  int r = lw / HWORDS, wr = lw % HWORDS;
  const unsigned int* base = p + (size_t)(r * HCHUNKS) * HWORDS + wr;
  unsigned int s0 = 0, s1 = 0, s2 = 0, s3 = 0;
  for (int c = 0; c < HCHUNKS; ++c) {
    unsigned int v = base[(size_t)c * HWORDS];
    s0 += v & 255u; s1 += (v >> 8) & 255u; s2 += (v >> 16) & 255u; s3 += v >> 24;
  }
  unsigned int d[4] = {s0, s1, s2, s3};
  int n0 = r * RANGE_NODES + wr * 4;
#pragma unroll
  for (int j = 0; j < 4; ++j) {
    int n = n0 + j;
    float f = (d[j] > 0) ? rsqrtf((float)d[j]) : 0.0f;
    if (is_dst) { dn[n] = f; ideg[n] = (int)d[j]; }
    else        { sn[n] = f; }
  }
}

// ---------------------------------------------------------------------------
// xb[n][k] = bf16( x[n][k] * sn[n] )  — prescaled bf16 gather operand.
// ---------------------------------------------------------------------------
__global__ __launch_bounds__(256) void convert_prescale_kernel(
    const float* __restrict__ x, const float* __restrict__ sn,
    unsigned int* __restrict__ xb2, int nquads) {
  int i = blockIdx.x * 256 + threadIdx.x;
  if (i >= nquads) return;
  float s = sn[i >> 4];                       // node = (i*4)/64
  float4 v = ((const float4*)x)[i];
  __hip_bfloat162 a = __float22bfloat162_rn(make_float2(v.x * s, v.y * s));
  __hip_bfloat162 b = __float22bfloat162_rn(make_float2(v.z * s, v.w * s));
  unsigned int wa, wb;
  __builtin_memcpy(&wa, &a, 4);
  __builtin_memcpy(&wb, &b, 4);
  ((uint2*)xb2)[i] = make_uint2(wa, wb);
}

// ---------------------------------------------------------------------------
// Exclusive scan, 3-kernel classic (n = 100000, nb = 391).
// ---------------------------------------------------------------------------
__global__ __launch_bounds__(SCAN_B) void scan_block_kernel(
    const int* __restrict__ in, int* __restrict__ out,
    int* __restrict__ bsum, int n) {
  __shared__ int s[SCAN_B];
  int t = threadIdx.x;
  int i = blockIdx.x * SCAN_B + t;
  int v = (i < n) ? in[i] : 0;
  s[t] = v;
  __syncthreads();
  for (int off = 1; off < SCAN_B; off <<= 1) {
    int add = (t >= off) ? s[t - off] : 0;
    __syncthreads();
    s[t] += add;
    __syncthreads();
  }
  if (i < n) out[i] = s[t] - v;
  if (t == SCAN_B - 1) bsum[blockIdx.x] = s[t];
}

__global__ __launch_bounds__(512) void scan_top_kernel(
    int* __restrict__ bsum, int nb) {
  __shared__ int s[512];
  int t = threadIdx.x;
  int v = (t < nb) ? bsum[t] : 0;
  s[t] = v;
  __syncthreads();
  for (int off = 1; off < 512; off <<= 1) {
    int add = (t >= off) ? s[t - off] : 0;
    __syncthreads();
    s[t] += add;
    __syncthreads();
  }
  if (t < nb) bsum[t] = s[t] - v;
}

__global__ __launch_bounds__(256) void scan_add_kernel(
    int* __restrict__ out, const int* __restrict__ bsum, int n, int total) {
  int i = blockIdx.x * blockDim.x + threadIdx.x;
  if (i < n) out[i] += bsum[i / SCAN_B];
  if (i == 0) out[n] = total;
}

// ---------------------------------------------------------------------------
// Partition edges into NBINS dst-bins.
// ---------------------------------------------------------------------------
__global__ __launch_bounds__(256) void bin_scatter_kernel(
    const int* __restrict__ src, const int* __restrict__ dst,
    const int* __restrict__ offsets, int* __restrict__ bin_cursor,
    int2* __restrict__ binned, int E) {
  __shared__ int cnt[NBINS];
  __shared__ int base[NBINS];
  int t = threadIdx.x;
  for (int i = t; i < NBINS; i += 256) cnt[i] = 0;
  __syncthreads();
  int per = (E + SCHUNKS - 1) / SCHUNKS;
  int beg = blockIdx.x * per;
  int end = min(beg + per, E);
  for (int i = beg + t; i < end; i += 256)
    atomicAdd(&cnt[dst[i] >> 9], 1);
  __syncthreads();
  for (int i = t; i < NBINS; i += 256) {
    base[i] = offsets[i << 9] + atomicAdd(&bin_cursor[i], cnt[i]);
    cnt[i] = 0;
  }
  __syncthreads();
  for (int i = beg + t; i < end; i += 256) {
    int s = src[i], d = dst[i];
    int b = d >> 9;
    int r = atomicAdd(&cnt[b], 1);
    binned[base[b] + r] = make_int2(s, d);
  }
}

// ---------------------------------------------------------------------------
// CSR fill, one block per bin.
// ---------------------------------------------------------------------------
__global__ __launch_bounds__(256) void fill_binned_kernel(
    const int2* __restrict__ binned, const int* __restrict__ offsets,
    int* __restrict__ csr_src) {
  __shared__ int cur[BINSZ];
  __shared__ int offs[BINSZ];
  int b = blockIdx.x;
  int t = threadIdx.x;
  int lo = b << 9;
  for (int i = t; i < BINSZ; i += 256) {
    cur[i] = 0;
    offs[i] = offsets[min(lo + i, N_NODES)];
  }
  __syncthreads();
  int w0 = offsets[lo];
  int w1 = offsets[min(lo + BINSZ, N_NODES)];
  for (int e = w0 + t; e < w1; e += 256) {
    int2 sd = binned[e];
    int r = atomicAdd(&cur[sd.y - lo], 1);
    csr_src[offs[sd.y - lo] + r] = sd.x;
  }
}

// ---------------------------------------------------------------------------
// bf16 helpers (proven numerics).
// ---------------------------------------------------------------------------
__device__ __forceinline__ float bf_lo(unsigned int u) {
  unsigned int x = u << 16; float f; __builtin_memcpy(&f, &x, 4); return f;
}
__device__ __forceinline__ float bf_hi(unsigned int u) {
  unsigned int x = u & 0xffff0000u; float f; __builtin_memcpy(&f, &x, 4); return f;
}
__device__ __forceinline__ unsigned short bf16bits(float f) {
  __hip_bfloat16 h = __float2bfloat16(f);
  unsigned short u; __builtin_memcpy(&u, &h, 2); return u;
}
// (x,y) f32 -> packed hi bf16x2 (truncated) + packed lo bf16x2 (residual, RNE)
__device__ __forceinline__ void cvt_pair_hl(float x, float y,
                                            unsigned int& hi, unsigned int& lo) {
  unsigned int u0, u1;
  __builtin_memcpy(&u0, &x, 4);
  __builtin_memcpy(&u1, &y, 4);
  unsigned int h0 = u0 & 0xffff0000u, h1 = u1 & 0xffff0000u;
  hi = (h0 >> 16) | h1;
  float hf0, hf1;
  __builtin_memcpy(&hf0, &h0, 4);
  __builtin_memcpy(&hf1, &h1, 4);
  __hip_bfloat162 l2 = __float22bfloat162_rn(make_float2(x - hf0, y - hf1));
  __builtin_memcpy(&lo, &l2, 4);
}

// ---------------------------------------------------------------------------
// Pre-stage W as hi/lo bf16 B-fragments into GLOBAL (16 KiB per table).
// Layout: entry e = ((hl*4 + nt)*2 + kt)*64 + lane, 8 shorts each.
// k = kt*32 + (lane>>4)*8 + j, c = nt*16 + (lane&15)  (proven layout).
// Block 0 -> W1 table, block 1 -> W2 table.
// ---------------------------------------------------------------------------
__global__ __launch_bounds__(256) void stage_wfrag_kernel(
    const float* __restrict__ W1, const float* __restrict__ W2,
    short* __restrict__ Wg) {
  const float* W = blockIdx.x ? W2 : W1;
  short* outp = Wg + blockIdx.x * 8192;
  int t = threadIdx.x;
  for (int e = t; e < 1024; e += 256) {
    int lidx = e & 63;
    int f = e >> 6;                       // 0..15
    int ktv = f & 1, ntv = (f >> 1) & 3, hl = f >> 3;
#pragma unroll
    for (int j = 0; j < 8; ++j) {
      int k = ktv * 32 + (lidx >> 4) * 8 + j;
      int c = ntv * 16 + (lidx & 15);
      float w = W[k * DIM + c];
      unsigned short hb = bf16bits(w);
      short val;
      if (hl == 0) {
        val = (short)hb;
      } else {
        unsigned int hx = (unsigned int)hb << 16;
        float hf; __builtin_memcpy(&hf, &hx, 4);
        val = (short)bf16bits(w - hf);
      }
      outp[e * 8 + j] = val;
    }
  }
}

// ---------------------------------------------------------------------------
// Fused layer v9: v8 + grid-stride residency fix.
//   v8 counters: occ 30% (one-shot blocks: 1563 launches x 1 batch/wave ->
//   ramp/tail churn), BW 1.9-2.3 TB/s. BW tracks resident waves (R5/R6).
//   Fix: grid = 1024 = exactly 4 blocks/CU (16 KiB LDS under 64 KiB pool);
//   each wave grid-strides ~6 batches -> steady 16 waves/CU.
//   Everything else byte-identical to v8 (best-verified structure):
//   - A staging in LDS [4][16][64] f32, XOR-swizzled both sides.
//   - W hi/lo bf16 B-frags from global table (L1-resident), per-batch
//     asm memory clobber blocks register-table hoisting.
//   - gather loop / frag layouts / 24-MFMA hi-lo pattern / epilogue proven.
// ---------------------------------------------------------------------------
template <bool PRESCALE, typename OUT_T>
__device__ __forceinline__ void epilogue_nt(
    float4v acc, float bv, int nb16, int kq, int lane, float snb,
    OUT_T* __restrict__ out, int nt) {
  int col = nt * 16 + (lane & 15);
#pragma unroll
  for (int r = 0; r < 4; ++r) {
    int node = nb16 + kq * 4 + r;          // C/D row = (lane>>4)*4 + reg
    float o = fmaxf(acc[r] + bv, 0.0f);
    if (PRESCALE) {
      o = o * __shfl(snb, kq * 4 + r);
      out[(long)node * DIM + col] = (OUT_T)__float2bfloat16(o);
    } else {
      out[(long)node * DIM + col] = (OUT_T)o;
    }
  }
}

template <bool PRESCALE, typename OUT_T>
__global__ __launch_bounds__(256, 4) void fused_layer_kernel(
    const __hip_bfloat16* __restrict__ xb, const int* __restrict__ csr_src,
    const int* __restrict__ offsets, const float* __restrict__ sn,
    const float* __restrict__ dn, const short* __restrict__ Wg,
    const float* __restrict__ bias, OUT_T* __restrict__ out, int N) {
  __shared__ __align__(16) float Astage[4][16][64];   // 16 KiB

  int t = threadIdx.x;
  int lane = t & 63;
  int wslot = t >> 6;          // 0..3
  int g = lane >> 4;           // edge sub-slot / MFMA k-group 0..3
  int q = lane & 15;           // feature quad / A-row (node-in-batch)

  float bias_nt[4];
#pragma unroll
  for (int nt = 0; nt < 4; ++nt) bias_nt[nt] = bias[nt * 16 + q];

  const uint2* __restrict__ xr = (const uint2*)xb;   // one row = 16 uint2
  const short8v* __restrict__ wfrag = (const short8v*)Wg;
  char* abase = (char*)&Astage[wslot][0][0];         // 256 B per node row

  int nwaves = gridDim.x * 4;
  for (int nb = blockIdx.x * 4 + wslot; nb < NBATCH; nb += nwaves) {
    asm volatile("" ::: "memory");   // no cross-batch hoist of W-frag loads
    int nb16 = nb * 16;
    int offv = offsets[nb16 + min(lane, 16)];
    float dnv = dn[nb16 + q];
    float snb = PRESCALE ? sn[nb16 + q] : 0.0f;

    // ---- gather 16 nodes (proven structure) ----
    for (int ni = 0; ni < 16; ++ni) {
      int beg = __shfl(offv, ni);
      int end = __shfl(offv, ni + 1);
      float a0 = 0.f, a1 = 0.f, a2 = 0.f, a3 = 0.f;
      for (int base = beg; base < end; base += 16) {
        int j0 = base + g;
        int jm = end - 1;
        bool p0 = j0 < end, p1 = j0 + 4 < end, p2 = j0 + 8 < end,
             p3 = j0 + 12 < end;
        int s0 = csr_src[min(j0, jm)];
        int s1 = csr_src[min(j0 + 4, jm)];
        int s2 = csr_src[min(j0 + 8, jm)];
        int s3 = csr_src[min(j0 + 12, jm)];
        uint2 v0 = make_uint2(0u, 0u), v1 = v0, v2 = v0, v3 = v0;
        if (p0) v0 = xr[(size_t)s0 * 16 + q];
        if (p1) v1 = xr[(size_t)s1 * 16 + q];
        if (p2) v2 = xr[(size_t)s2 * 16 + q];
        if (p3) v3 = xr[(size_t)s3 * 16 + q];
        a0 += bf_lo(v0.x); a1 += bf_hi(v0.x); a2 += bf_lo(v0.y); a3 += bf_hi(v0.y);
        a0 += bf_lo(v1.x); a1 += bf_hi(v1.x); a2 += bf_lo(v1.y); a3 += bf_hi(v1.y);
        a0 += bf_lo(v2.x); a1 += bf_hi(v2.x); a2 += bf_lo(v2.y); a3 += bf_hi(v2.y);
        a0 += bf_lo(v3.x); a1 += bf_hi(v3.x); a2 += bf_lo(v3.y); a3 += bf_hi(v3.y);
      }
      a0 += __shfl_xor(a0, 16); a1 += __shfl_xor(a1, 16);
      a2 += __shfl_xor(a2, 16); a3 += __shfl_xor(a3, 16);
      a0 += __shfl_xor(a0, 32); a1 += __shfl_xor(a1, 32);
      a2 += __shfl_xor(a2, 32); a3 += __shfl_xor(a3, 32);

      float dnw = __shfl(dnv, ni);
      if (lane < 16) {
        // quad q of node ni at swizzled slot (both sides use same involution)
        int woff = ni * 256 + ((lane * 16) ^ ((ni & 15) << 4));
        *(float4*)(abase + woff) =
            make_float4(a0 * dnw, a1 * dnw, a2 * dnw, a3 * dnw);
      }
    }

    // ---- project: read A rows (same-wave LDS, lgkm-ordered), 24 MFMA ----
    float4v acc0 = {0.f, 0.f, 0.f, 0.f}, acc1 = acc0, acc2 = acc0, acc3 = acc0;
#pragma unroll
    for (int kt = 0; kt < 2; ++kt) {
      int o1 = kt * 128 + g * 32;     // feats kt*32+8g.. of node q
      float4 fa = *(const float4*)(abase + q * 256 + (o1 ^ (q << 4)));
      float4 fb = *(const float4*)(abase + q * 256 + ((o1 + 16) ^ (q << 4)));
      union { unsigned int w[4]; short8v v; } Uh, Ul;
      cvt_pair_hl(fa.x, fa.y, Uh.w[0], Ul.w[0]);
      cvt_pair_hl(fa.z, fa.w, Uh.w[1], Ul.w[1]);
      cvt_pair_hl(fb.x, fb.y, Uh.w[2], Ul.w[2]);
      cvt_pair_hl(fb.z, fb.w, Uh.w[3], Ul.w[3]);
      short8v ahi = Uh.v, alo = Ul.v;
#define PROJ_NT(NT, ACC)                                                      \
      {                                                                       \
        short8v bh = wfrag[(((NT) * 2) + kt) * 64 + lane];                    \
        short8v bl = wfrag[(((4 + (NT)) * 2) + kt) * 64 + lane];              \
        ACC = __builtin_amdgcn_mfma_f32_16x16x32_bf16(ahi, bh, ACC, 0, 0, 0); \
        ACC = __builtin_amdgcn_mfma_f32_16x16x32_bf16(alo, bh, ACC, 0, 0, 0); \
        ACC = __builtin_amdgcn_mfma_f32_16x16x32_bf16(ahi, bl, ACC, 0, 0, 0); \
      }
      PROJ_NT(0, acc0)
      PROJ_NT(1, acc1)
      PROJ_NT(2, acc2)
      PROJ_NT(3, acc3)
#undef PROJ_NT
    }

    float snbv = PRESCALE ? snb : 0.0f;
    epilogue_nt<PRESCALE, OUT_T>(acc0, bias_nt[0], nb16, g, lane, snbv, out, 0);
    epilogue_nt<PRESCALE, OUT_T>(acc1, bias_nt[1], nb16, g, lane, snbv, out, 1);
    epilogue_nt<PRESCALE, OUT_T>(acc2, bias_nt[2], nb16, g, lane, snbv, out, 2);
    epilogue_nt<PRESCALE, OUT_T>(acc3, bias_nt[3], nb16, g, lane, snbv, out, 3);
  }
}

extern "C" void kernel_launch(void* const* d_in, const int* in_sizes, int n_in,
                              void* d_out, int out_size, void* d_ws, size_t ws_size,
                              hipStream_t stream) {
  const float* x        = (const float*)d_in[0];
  const int*   edge_src = (const int*)d_in[1];
  const int*   edge_dst = (const int*)d_in[2];
  const float* W1       = (const float*)d_in[3];
  const float* b1       = (const float*)d_in[4];
  const float* W2       = (const float*)d_in[5];
  const float* b2       = (const float*)d_in[6];
  float* out = (float*)d_out;

  const int E = in_sizes[1];
  const int N = N_NODES;
  const int NB = (N + SCAN_B - 1) / SCAN_B;   // 391

  // Workspace (4B units), ~33.6 MB total. regionB time-shared:
  //   partials (hist..reduce) -> binned (bin_scatter..fill) -> h1b (layers)
  // ideg time-shared: degree counts (reduce..scan_block) -> W frag tables.
  float* sn         = (float*)d_ws;                  // N
  float* dn         = sn + N;                        // N
  int*   ideg       = (int*)(dn + N);                // N
  int*   offsets    = ideg + N;                      // N+1
  int*   bsum       = offsets + (N + 1);             // 512
  int*   bin_cursor = bsum + 512;                    // 256
  int*   csr_src    = bin_cursor + 256;              // E
  unsigned int* xb_raw = (unsigned int*)(csr_src + E);       // N*DIM/2 (12.8MB)
  unsigned int* regionB = xb_raw + (size_t)N * DIM / 2;      // 12.8MB
  unsigned int* partials = regionB;                          // 256*HWORDS
  int2*  binned   = (int2*)regionB;                  // E int2
  __hip_bfloat16* xb  = (__hip_bfloat16*)xb_raw;
  __hip_bfloat16* h1b = (__hip_bfloat16*)regionB;
  short* Wg = (short*)ideg;                          // 2 x 8192 shorts (32 KB)

  hipMemsetAsync(bin_cursor, 0, 256 * sizeof(int), stream);

  // --- degrees + norms (no global atomics) ---
  hist_kernel<<<256, 256, 0, stream>>>(edge_src, edge_dst, E, partials);
  reduce_norm_kernel<<<(2 * (N / 4) + 255) / 256, 256, 0, stream>>>(
      partials, partials + (size_t)128 * HWORDS, sn, dn, ideg);

  // --- prescaled bf16 copy of x ---
  {
    int nquads = N * DIM / 4;
    convert_prescale_kernel<<<(nquads + 255) / 256, 256, 0, stream>>>(
        x, sn, xb_raw, nquads);
  }

  // --- offsets = exclusive scan of in-degree ---
  scan_block_kernel<<<NB, SCAN_B, 0, stream>>>(ideg, offsets, bsum, N);
  // ideg dead after scan_block: overwrite with W fragment tables
  stage_wfrag_kernel<<<2, 256, 0, stream>>>(W1, W2, Wg);
  scan_top_kernel<<<1, 512, 0, stream>>>(bsum, NB);
  scan_add_kernel<<<(N + 255) / 256, 256, 0, stream>>>(offsets, bsum, N, E);

  // --- binned CSR build (overwrites partials region — dead after reduce) ---
  bin_scatter_kernel<<<SCHUNKS, 256, 0, stream>>>(edge_src, edge_dst, offsets,
                                                  bin_cursor, binned, E);
  fill_binned_kernel<<<NBINS, 256, 0, stream>>>(binned, offsets, csr_src);

  const int fb = 1024;   // 4 blocks/CU exactly; grid-stride ~6 batches/wave

  // --- layer 1: xb -> h1b (bf16, prescaled by sn; overwrites binned) ---
  fused_layer_kernel<true, __hip_bfloat16><<<fb, 256, 0, stream>>>(
      xb, csr_src, offsets, sn, dn, Wg, b1, h1b, N);

  // --- layer 2: h1b -> out (fp32) ---
  fused_layer_kernel<false, float><<<fb, 256, 0, stream>>>(
      h1b, csr_src, offsets, sn, dn, Wg + 8192, b2, out, N);
}